// Round 10
// baseline (199.236 us; speedup 1.0000x reference)
//
#include <hip/hip_runtime.h>
#include <hip/hip_bf16.h>

// ---------------------------------------------------------------------------
// GCN 4-layer forward on MI355X.
//   - R6: single-pass SLOTTED CSR build (one device atomic per (bin,tile)).
//     Property used by R21/R23: an aligned node block's edges are CONTIGUOUS
//     in the edges[] array (per-bin dst-local scan; 32|512 and 256|512).
//   - R5/R7: float4 gathers, 8-edge unroll.
//   - R10/R11 LDS bank law: AP=33 odd stride -> conflict-free staging.
//   - R12: mega-fusion (agg+GEMM1+GEMM2 in one kernel; h1/agg1/h2 never HBM).
//   - R13 FAILURE: unrolled chunk loops -> compiler pipelined W-loads across
//     barriers -> 256 VGPR + spill. R14 fix: '#pragma unroll 1' chunk loops.
//   - R15 FAILURE: BM 32->64 -> 16 waves/CU -> 98us. Latency-hiding limited.
//   - R18 WIN: 4KB register-dbuf W chunks -> 20.9KB, 28 waves, 76.5us.
//   - R19/R20 FAILURES: forced 8 waves/EU (VGPR 32, MLP collapse); swizzle
//     overhead. R22 FAILURE: W direct-from-global (no prefetch) -> L2 latency
//     in loop-carried dep -> 111us. Prefetch-ahead of W is load-bearing.
//   - R21 WIN: LDS edge staging (fused1/fused2/aggw4). 182us. R23: aggpool
//     staging null (feature-bound).
//   - R24 (this round): 512-THREAD blocks for fused1/fused2. Gather was 2
//     serial passes (256t x 16 lanes = 16 rows/pass); 512t does all 32 rows
//     in ONE pass -> gather critical path halves. Thread-cap occupancy: 4
//     blk x 8 waves = 32 waves/CU. W chunks 8KB (4 chunks per W), register
//     double-buffered. Per-thread acc shrinks (2x4 / 1x4) -> VGPR stays low.
//   - pool: wave segmented scan on sorted gid (R1: contended atomics 152us).
// ---------------------------------------------------------------------------

#define TILE 4096   // edges per build tile (256 threads x 16)
#define SLOT 8192   // per-bin slot capacity (bin = 512 nodes, mean ~4080 edges)

// --- build pass 1: tile->LDS, histogram, reserve slot space, scatter -------
__global__ __launch_bounds__(256) void k_buildbins(
        const int* __restrict__ src, const int* __restrict__ dst, int E, int NBIN,
        int* __restrict__ cntD, int* __restrict__ cntS,
        int* __restrict__ bucketD, unsigned short* __restrict__ bucketS) {
    __shared__ int ssrc[TILE];
    __shared__ int sdst[TILE];
    __shared__ int hD[256], hS[256], bD[256], bS[256];
    int t = threadIdx.x;
    hD[t] = 0; hS[t] = 0;
    __syncthreads();
    int base = blockIdx.x * TILE;
    int lim = min(TILE, E - base);
#pragma unroll
    for (int k = 0; k < TILE / 256; k++) {
        int i = k * 256 + t;
        if (i < lim) {
            int d = dst[base + i], sv = src[base + i];
            sdst[i] = d; ssrc[i] = sv;
            atomicAdd(&hD[d >> 9], 1);
            atomicAdd(&hS[sv >> 9], 1);
        }
    }
    __syncthreads();
    if (t < NBIN) {
        bD[t] = (hD[t] > 0) ? atomicAdd(&cntD[t], hD[t]) : 0;
        bS[t] = (hS[t] > 0) ? atomicAdd(&cntS[t], hS[t]) : 0;
        hD[t] = 0; hS[t] = 0;
    }
    __syncthreads();
#pragma unroll
    for (int k = 0; k < TILE / 256; k++) {
        int i = k * 256 + t;
        if (i < lim) {
            int d = sdst[i], sv = ssrc[i];
            int binD = d >> 9, binS = sv >> 9;
            int pD = atomicAdd(&hD[binD], 1) + bD[binD];
            bucketD[binD * SLOT + pD] = (sv << 9) | (d & 511);
            int pS = atomicAdd(&hS[binS], 1) + bS[binS];
            bucketS[binS * SLOT + pS] = (unsigned short)(sv & 511);
        }
    }
}

// --- build pass 2: per-src-bucket LDS count -> norm_out --------------------
__global__ __launch_bounds__(256) void k_degout(const unsigned short* __restrict__ bucketS,
                                                const int* __restrict__ cntS,
                                                int N, float* __restrict__ norm_out) {
    __shared__ int cnt[512];
    int t = threadIdx.x;
    cnt[t] = 0; cnt[t + 256] = 0;
    __syncthreads();
    int bin = blockIdx.x;
    int b0 = bin * SLOT, cn = cntS[bin];
    for (int j = t; j < cn; j += 256) atomicAdd(&cnt[bucketS[b0 + j]], 1);
    __syncthreads();
    int base = bin << 9;
    for (int l = t; l < 512; l += 256) {
        int g = base + l;
        if (g < N) norm_out[g] = rsqrtf(fmaxf((float)cnt[l], 1.0f));
    }
}

// --- build pass 3: per-dst-bucket count+scan -> rowBE/norm_in, place edges -
__global__ __launch_bounds__(256) void k_build(const int* __restrict__ bucketD,
                                               const int* __restrict__ cntDg,
                                               const float* __restrict__ norm_out,
                                               int N, int2* __restrict__ rowBE,
                                               float* __restrict__ norm_in,
                                               int2* __restrict__ edges) {
    __shared__ int cnt[512], sc[512];
    int t = threadIdx.x;
    cnt[t] = 0; cnt[t + 256] = 0;
    __syncthreads();
    int bin = blockIdx.x;
    int b0 = bin * SLOT, cn = cntDg[bin];
    for (int j = t; j < cn; j += 256) atomicAdd(&cnt[bucketD[b0 + j] & 511], 1);
    __syncthreads();
    sc[t] = cnt[t]; sc[t + 256] = cnt[t + 256];
    __syncthreads();
    for (int off = 1; off < 512; off <<= 1) {
        int v0 = (t >= off) ? sc[t - off] : 0;
        int i1 = t + 256;
        int v1 = sc[i1 - off];   // i1 >= 256 >= off always
        __syncthreads();
        sc[t] += v0; sc[i1] += v1;
        __syncthreads();
    }
    int base = bin << 9;
    for (int l = t; l < 512; l += 256) {
        int g = base + l;
        int e = sc[l] - cnt[l];          // exclusive within bucket
        if (g < N) {
            rowBE[g] = make_int2(b0 + e, b0 + sc[l]);
            norm_in[g] = rsqrtf(fmaxf((float)cnt[l], 1.0f));
        }
        cnt[l] = e;                      // becomes placement cursor
    }
    __syncthreads();
    for (int j = t; j < cn; j += 256) {
        int p = bucketD[b0 + j];
        int sv = p >> 9, dl = p & 511;
        int pos = atomicAdd(&cnt[dl], 1);
        edges[b0 + pos] = make_int2(sv, __float_as_int(norm_out[sv]));
    }
}

// shared gather primitive: sum_e w_e * h4[src_e*G + lane], 8-edge unroll.
// 'eb' may point to GLOBAL edges or an LDS-staged copy (forceinline ->
// addrspace inferred at each call site).
template <int G>
__device__ __forceinline__ float4 gather_row(const float4* __restrict__ h4,
                                             const int2* eb,
                                             int j, int end, int lane) {
    float4 acc = make_float4(0.f, 0.f, 0.f, 0.f);
    for (; j + 7 < end; j += 8) {
        int2 e[8];
        float4 v[8];
#pragma unroll
        for (int q = 0; q < 8; q++) e[q] = eb[j + q];
#pragma unroll
        for (int q = 0; q < 8; q++) v[q] = h4[(size_t)e[q].x * G + lane];
#pragma unroll
        for (int q = 0; q < 8; q++) {
            float wq = __int_as_float(e[q].y);
            acc.x += v[q].x * wq; acc.y += v[q].y * wq;
            acc.z += v[q].z * wq; acc.w += v[q].w * wq;
        }
    }
    if (j + 3 < end) {
        int2 e0 = eb[j], e1 = eb[j + 1], e2 = eb[j + 2], e3 = eb[j + 3];
        float4 v0 = h4[(size_t)e0.x * G + lane];
        float4 v1 = h4[(size_t)e1.x * G + lane];
        float4 v2 = h4[(size_t)e2.x * G + lane];
        float4 v3 = h4[(size_t)e3.x * G + lane];
        float w0 = __int_as_float(e0.y), w1 = __int_as_float(e1.y);
        float w2 = __int_as_float(e2.y), w3 = __int_as_float(e3.y);
        acc.x += v0.x * w0 + v1.x * w1 + v2.x * w2 + v3.x * w3;
        acc.y += v0.y * w0 + v1.y * w1 + v2.y * w2 + v3.y * w3;
        acc.z += v0.z * w0 + v1.z * w1 + v2.z * w2 + v3.z * w3;
        acc.w += v0.w * w0 + v1.w * w1 + v2.w * w2 + v3.w * w3;
        j += 4;
    }
    for (; j < end; j++) {
        int2 e = eb[j];
        float4 v = h4[(size_t)e.x * G + lane];
        float w0 = __int_as_float(e.y);
        acc.x += v.x * w0; acc.y += v.y * w0; acc.z += v.z * w0; acc.w += v.w * w0;
    }
    return acc;
}

// --- L1+L2 fused, BM=32, 512 THREADS (R24). Gather: 32 rows x 16 lanes in
// ONE pass (was 2 serial passes at 256t). GEMM1 32x128 (2x4/thread), GEMM2
// 32x64 (1x4/thread). W in 8KB chunks (4 per W), REGISTER double-buffered
// ('#pragma unroll 1', R13; prefetch-ahead load-bearing, R22). Edge range
// staged into Wlds (dead during gather). LDS = 16.9 + 8 = 24.9KB ->
// 4 blk/CU x 8 waves = 32 waves (thread-cap).
__global__ __launch_bounds__(512) void k_fused1(const float4* __restrict__ x4,
                        const int2* __restrict__ edges, const int2* __restrict__ rowBE,
                        const float* __restrict__ norm, const float* __restrict__ W1,
                        const float* __restrict__ b1, const float* __restrict__ W2,
                        int N, float* __restrict__ t2) {
    constexpr int AP = 33;                 // float4 slots per k4; AP%8==1 -> free staging
    constexpr int ECAP = 1024;             // 8KB of int2 = Wlds footprint
    __shared__ float4 Alds[32 * AP];       // phase1: [k4<16][r<32] ; phase2: [k4<32][r<32]
    __shared__ float  Wlds[2048];          // 8KB W chunk; edge stage during gather
    int2* Elds = (int2*)Wlds;
    int t = threadIdx.x;
    int row0 = blockIdx.x * 32;
    const float4* W1v = (const float4*)W1;
    const float4* W2v = (const float4*)W2;
    float4 wreg = W1v[t];                  // W1 chunk 0 (8KB) prefetch rides under staging+gather
    // stage this block's contiguous edge range (rows in one bin => ranges
    // are consecutive; 32-aligned blocks never straddle a 512-bin)
    int lastRow = min(row0 + 31, N - 1);
    int eBase = rowBE[row0].x;
    int eLim = min(rowBE[lastRow].y - eBase, ECAP);
    for (int j = t; j < eLim; j += 512) Elds[j] = edges[eBase + j];
    __syncthreads();
    // gather: ALL 32 rows x 16 float4-lanes in one pass (single latency round)
    {
        int r = t >> 4;                    // 0..31
        int lane = t & 15;
        int node = row0 + r;
        float4 acc = make_float4(0.f, 0.f, 0.f, 0.f);
        if (node < N) {
            int2 be = rowBE[node];
            if (be.y - eBase <= eLim)      // fully staged (always, in practice)
                acc = gather_row<16>(x4, Elds, be.x - eBase, be.y - eBase, lane);
            else                           // overflow fallback
                acc = gather_row<16>(x4, edges, be.x, be.y, lane);
            float s = norm[node];
            acc.x *= s; acc.y *= s; acc.z *= s; acc.w *= s;
        }
        Alds[lane * AP + r] = acc;
    }
    // GEMM1: 32x64 @ 64x128, 2x4/thread (tx<32 colquad, ty<16 rowgroup);
    // W1 (32KB) in 4 chunks of 16 k-rows (8KB), register double-buffered.
    // First barrier also fences Elds reads before Wlds overwrite.
    int tx = t & 31, ty = t >> 5;
    float acc1[2][4] = {};
#pragma unroll 1
    for (int c = 0; c < 4; c++) {
        __syncthreads();                   // prev chunk readers / gather+Elds done
        ((float4*)Wlds)[t] = wreg;
        __syncthreads();
        if (c < 3) wreg = W1v[(c + 1) * 512 + t];   // next chunk under compute
#pragma unroll
        for (int k4l = 0; k4l < 4; k4l++) {
            int k4 = c * 4 + k4l;
            float4 a0 = Alds[k4 * AP + ty * 2 + 0];
            float4 a1 = Alds[k4 * AP + ty * 2 + 1];
            const float* wb = &Wlds[(k4l * 4) * 128 + tx * 4];
            float4 w0 = *(const float4*)(wb);
            float4 w1 = *(const float4*)(wb + 128);
            float4 w2 = *(const float4*)(wb + 256);
            float4 w3 = *(const float4*)(wb + 384);
#define GSTEP(AK, WV) \
            acc1[0][0] += a0.AK * WV.x; acc1[0][1] += a0.AK * WV.y; acc1[0][2] += a0.AK * WV.z; acc1[0][3] += a0.AK * WV.w; \
            acc1[1][0] += a1.AK * WV.x; acc1[1][1] += a1.AK * WV.y; acc1[1][2] += a1.AK * WV.z; acc1[1][3] += a1.AK * WV.w;
            GSTEP(x, w0) GSTEP(y, w1) GSTEP(z, w2) GSTEP(w, w3)
#undef GSTEP
        }
    }
    __syncthreads();                       // last GEMM1 A/W reads done
    float4 bb = *(const float4*)(b1 + tx * 4);
    wreg = W2v[t];                         // W2 chunk 0 prefetch rides under H1 store
    float4 h[2];
#pragma unroll
    for (int i = 0; i < 2; i++) {
        h[i].x = fmaxf(acc1[i][0] + bb.x, 0.f);
        h[i].y = fmaxf(acc1[i][1] + bb.y, 0.f);
        h[i].z = fmaxf(acc1[i][2] + bb.z, 0.f);
        h[i].w = fmaxf(acc1[i][3] + bb.w, 0.f);
    }
#pragma unroll
    for (int i = 0; i < 2; i++) Alds[tx * AP + ty * 2 + i] = h[i];   // H1: [k4=tx][r]
    // GEMM2: 32x128 @ 128x64, 1x4/thread (tx2<16 colquad, ty2<32 row);
    // W2 (32KB) in 4 chunks of 32 k-rows (8KB), register double-buffered
    int tx2 = t & 15, ty2 = t >> 4;
    float acc2[4] = {};
#pragma unroll 1
    for (int c = 0; c < 4; c++) {
        __syncthreads();                   // publishes H1 (c==0) / prev readers done
        ((float4*)Wlds)[t] = wreg;
        __syncthreads();
        if (c < 3) wreg = W2v[(c + 1) * 512 + t];
#pragma unroll
        for (int k4l = 0; k4l < 8; k4l++) {
            int k4 = c * 8 + k4l;
            float4 a = Alds[k4 * AP + ty2];
            const float* wb = &Wlds[(k4l * 4) * 64 + tx2 * 4];
            float4 w0 = *(const float4*)(wb);
            float4 w1 = *(const float4*)(wb + 64);
            float4 w2 = *(const float4*)(wb + 128);
            float4 w3 = *(const float4*)(wb + 192);
            acc2[0] += a.x * w0.x + a.y * w1.x + a.z * w2.x + a.w * w3.x;
            acc2[1] += a.x * w0.y + a.y * w1.y + a.z * w2.y + a.w * w3.y;
            acc2[2] += a.x * w0.z + a.y * w1.z + a.z * w2.z + a.w * w3.z;
            acc2[3] += a.x * w0.w + a.y * w1.w + a.z * w2.w + a.w * w3.w;
        }
    }
    {
        int grow = row0 + ty2;
        if (grow < N) {
            float4 o = make_float4(acc2[0], acc2[1], acc2[2], acc2[3]);
            *(float4*)(t2 + (size_t)grow * 64 + tx2 * 4) = o;
        }
    }
}

// --- L2-agg + L3 fused, BM=32, 512 THREADS: per 32-row block:
//   H2 = relu(agg(t2)*norm + b2)  (single-pass gather -> LDS, edges in Wlds)
//   t3 = H2@W3                    (first 256 threads; tiny GEMM)
// W3 (8KB) prefetched into 1 reg/thread during staging+gather. LDS 16.6KB.
__global__ __launch_bounds__(512) void k_fused2(const float4* __restrict__ t2_4,
                        const int2* __restrict__ edges, const int2* __restrict__ rowBE,
                        const float* __restrict__ norm, const float* __restrict__ b2,
                        const float* __restrict__ W3, int N, float* __restrict__ t3) {
    constexpr int AP = 33;
    constexpr int ECAP = 1024;             // 8KB of int2 = Wlds footprint
    __shared__ float4 Alds[16 * AP];       // [k4<16][r<32]
    __shared__ float  Wlds[64 * 32];       // W3 (8KB); edge stage during gather
    int2* Elds = (int2*)Wlds;
    int t = threadIdx.x;
    int row0 = blockIdx.x * 32;
    float4 wr0 = ((const float4*)W3)[t];       // W3 prefetch rides under staging+gather
    int lastRow = min(row0 + 31, N - 1);
    int eBase = rowBE[row0].x;
    int eLim = min(rowBE[lastRow].y - eBase, ECAP);
    for (int j = t; j < eLim; j += 512) Elds[j] = edges[eBase + j];
    __syncthreads();
    // gather: ALL 32 rows x 16 lanes, one pass
    {
        int r = t >> 4;
        int lane = t & 15;
        int node = row0 + r;
        float4 acc = make_float4(0.f, 0.f, 0.f, 0.f);
        if (node < N) {
            int2 be = rowBE[node];
            if (be.y - eBase <= eLim)
                acc = gather_row<16>(t2_4, Elds, be.x - eBase, be.y - eBase, lane);
            else
                acc = gather_row<16>(t2_4, edges, be.x, be.y, lane);
            float s = norm[node];
            float4 b = ((const float4*)b2)[lane];
            acc.x = fmaxf(acc.x * s + b.x, 0.f);
            acc.y = fmaxf(acc.y * s + b.y, 0.f);
            acc.z = fmaxf(acc.z * s + b.z, 0.f);
            acc.w = fmaxf(acc.w * s + b.w, 0.f);
        }
        Alds[lane * AP + r] = acc;
    }
    __syncthreads();                       // all Elds reads done before W3 overwrite
    ((float4*)Wlds)[t] = wr0;
    __syncthreads();
    // GEMM3: 32x64 @ 64x32, 1 row x 4 cols/thread (tx<8, ty<32); t<256 active
    if (t < 256) {
        int tx = t & 7, ty = t >> 3;
        float acc3[4] = {};
#pragma unroll 2
        for (int k4 = 0; k4 < 16; k4++) {
            float4 a = Alds[k4 * AP + ty];
            const float* wb = &Wlds[(k4 * 4) * 32 + tx * 4];
            float4 w0 = *(const float4*)(wb);
            float4 w1 = *(const float4*)(wb + 32);
            float4 w2 = *(const float4*)(wb + 64);
            float4 w3 = *(const float4*)(wb + 96);
            acc3[0] += a.x * w0.x + a.y * w1.x + a.z * w2.x + a.w * w3.x;
            acc3[1] += a.x * w0.y + a.y * w1.y + a.z * w2.y + a.w * w3.y;
            acc3[2] += a.x * w0.z + a.y * w1.z + a.z * w2.z + a.w * w3.z;
            acc3[3] += a.x * w0.w + a.y * w1.w + a.z * w2.w + a.w * w3.w;
        }
        int grow = row0 + ty;
        if (grow < N) {
            float4 o = make_float4(acc3[0], acc3[1], acc3[2], acc3[3]);
            *(float4*)(t3 + (size_t)grow * 32 + tx * 4) = o;
        }
    }
}

// agg3 + W4 fused (D=32): h3 = relu(agg(t3)*norm+b3) in regs (never stored),
// t4[node] = h3 @ W4 via per-lane partials + 8-lane __shfl_xor reduce.
// R21: edges staged into dedicated 4KB LDS (kernel is far below LDS cap).
__global__ __launch_bounds__(256) void k_aggw4(const float4* __restrict__ h4,
                        const int2* __restrict__ edges, const int2* __restrict__ rowBE,
                        const float* __restrict__ norm, const float4* __restrict__ b3_4,
                        const float* __restrict__ W4, int n, float4* __restrict__ t4) {
    __shared__ float w[128];
    __shared__ int2 Elds[512];
    int t = threadIdx.x;
    if (t < 128) w[t] = W4[t];
    int row0 = blockIdx.x * 32;
    int lastRow = min(row0 + 31, n - 1);
    int eBase = rowBE[row0].x;
    int eLim = min(rowBE[lastRow].y - eBase, 512);
    for (int j = t; j < eLim; j += 256) Elds[j] = edges[eBase + j];
    __syncthreads();
    int node = row0 + t / 8;
    int lane = t % 8;
    if (node >= n) return;
    float4 wr0 = ((const float4*)w)[4 * lane + 0];
    float4 wr1 = ((const float4*)w)[4 * lane + 1];
    float4 wr2 = ((const float4*)w)[4 * lane + 2];
    float4 wr3 = ((const float4*)w)[4 * lane + 3];
    int2 be = rowBE[node];
    float4 acc;
    if (be.y - eBase <= eLim)
        acc = gather_row<8>(h4, Elds, be.x - eBase, be.y - eBase, lane);
    else
        acc = gather_row<8>(h4, edges, be.x, be.y, lane);
    float s = norm[node];
    float4 b = b3_4[lane];
    float hx = fmaxf(acc.x * s + b.x, 0.f);
    float hy = fmaxf(acc.y * s + b.y, 0.f);
    float hz = fmaxf(acc.z * s + b.z, 0.f);
    float hw = fmaxf(acc.w * s + b.w, 0.f);
    float4 p;
    p.x = hx * wr0.x + hy * wr1.x + hz * wr2.x + hw * wr3.x;
    p.y = hx * wr0.y + hy * wr1.y + hz * wr2.y + hw * wr3.y;
    p.z = hx * wr0.z + hy * wr1.z + hz * wr2.z + hw * wr3.z;
    p.w = hx * wr0.w + hy * wr1.w + hz * wr2.w + hw * wr3.w;
#pragma unroll
    for (int m = 1; m < 8; m <<= 1) {
        p.x += __shfl_xor(p.x, m);
        p.y += __shfl_xor(p.y, m);
        p.z += __shfl_xor(p.z, m);
        p.w += __shfl_xor(p.w, m);
    }
    if (lane == 0) t4[node] = p;
}

// L4 fused: per node (1 thread): acc = sum_e t4[src_e]*w_e ; v = acc*norm+b4 ;
// wave segmented-scan pool on sorted gid -> atomics.
// R23: block covers 256 nodes = half a 512-bin -> contiguous edge range;
// stage into 24KB LDS (grid ~1.5 blocks/CU, LDS is free capacity here).
__global__ __launch_bounds__(256) void k_aggpool(const float4* __restrict__ t4,
                        const int2* __restrict__ edges, const int2* __restrict__ rowBE,
                        const float* __restrict__ norm, const float* __restrict__ b4,
                        const int* __restrict__ gid, int N,
                        float* __restrict__ sums, float* __restrict__ counts) {
    constexpr int ECAP = 3072;             // 24KB; mean 2048 edges/block, >>6 sigma
    __shared__ int2 Elds[ECAP];
    int t = threadIdx.x;
    int row0 = blockIdx.x * blockDim.x;    // row0 < N guaranteed by grid
    int lastRow = min(row0 + 255, N - 1);
    int eBase = rowBE[row0].x;
    int eLim = min(rowBE[lastRow].y - eBase, ECAP);
    for (int j = t; j < eLim; j += 256) Elds[j] = edges[eBase + j];
    __syncthreads();
    int n = row0 + t;
    int lane = t & 63;
    bool valid = (n < N);
    float v0 = 0.f, v1 = 0.f, v2 = 0.f, v3 = 0.f, cnt = 0.f;
    int g = -1;
    if (valid) {
        g = gid[n];
        int2 be = rowBE[n];
        float4 acc;
        if (be.y - eBase <= eLim)
            acc = gather_row<1>(t4, Elds, be.x - eBase, be.y - eBase, 0);
        else
            acc = gather_row<1>(t4, edges, be.x, be.y, 0);
        float s = norm[n];
        v0 = acc.x * s + b4[0];
        v1 = acc.y * s + b4[1];
        v2 = acc.z * s + b4[2];
        v3 = acc.w * s + b4[3];
        cnt = 1.f;
    }
#pragma unroll
    for (int off = 1; off < 64; off <<= 1) {
        float u0 = __shfl_up(v0, off);
        float u1 = __shfl_up(v1, off);
        float u2 = __shfl_up(v2, off);
        float u3 = __shfl_up(v3, off);
        float uc = __shfl_up(cnt, off);
        int   ug = __shfl_up(g, off);
        if (lane >= off && ug == g) { v0 += u0; v1 += u1; v2 += u2; v3 += u3; cnt += uc; }
    }
    int gnext = __shfl_down(g, 1);
    bool boundary = (lane == 63) || (gnext != g);
    if (boundary && valid) {
        atomicAdd(&sums[g * 4 + 0], v0);
        atomicAdd(&sums[g * 4 + 1], v1);
        atomicAdd(&sums[g * 4 + 2], v2);
        atomicAdd(&sums[g * 4 + 3], v3);
        atomicAdd(&counts[g], cnt);
    }
}

__global__ void k_div(const float* __restrict__ sums, const float* __restrict__ counts,
                      int G, float* __restrict__ out) {
    int idx = blockIdx.x * blockDim.x + threadIdx.x;
    if (idx >= G * 4) return;
    out[idx] = sums[idx] / fmaxf(counts[idx >> 2], 1.0f);
}

extern "C" void kernel_launch(void* const* d_in, const int* in_sizes, int n_in,
                              void* d_out, int out_size, void* d_ws, size_t ws_size,
                              hipStream_t stream) {
    const float* x  = (const float*)d_in[0];
    const float* W1 = (const float*)d_in[1];
    const float* b1 = (const float*)d_in[2];
    const float* W2 = (const float*)d_in[3];
    const float* b2 = (const float*)d_in[4];
    const float* W3 = (const float*)d_in[5];
    const float* b3 = (const float*)d_in[6];
    const float* W4 = (const float*)d_in[7];
    const float* b4 = (const float*)d_in[8];
    const int* src = (const int*)d_in[9];
    const int* dst = (const int*)d_in[10];
    const int* gid = (const int*)d_in[11];

    const int N = in_sizes[0] / 64;
    const int E = in_sizes[9];
    const int G = out_size / 4;
    const int NP = ((N + 63) / 64) * 64;
    const int NBIN = (N + 511) >> 9;          // coarse bins (<=256 for N<=131072)
    const int T = (E + TILE - 1) / TILE;      // build tiles

    char* ws = (char*)d_ws;
    size_t off = 0;
    auto alloc = [&](size_t bytes) -> void* {
        void* p = (void*)(ws + off);
        off += (bytes + 255) & ~(size_t)255;
        return p;
    };
    float* sums     = (float*)alloc(2048 * 4);   // 500*4 used
    float* counts   = (float*)alloc(512 * 4);
    int*   cntD     = (int*)alloc(256 * 4);
    int*   cntS     = (int*)alloc(256 * 4);
    int*   bucketD  = (int*)alloc((size_t)NBIN * SLOT * 4);
    unsigned short* bucketS = (unsigned short*)alloc((size_t)NBIN * SLOT * 2);
    int2*  edges    = (int2*)alloc((size_t)NBIN * SLOT * 8);
    int2*  rowBE    = (int2*)alloc((size_t)NP * 8);
    float* norm_out = (float*)alloc((size_t)NP * 4);
    float* norm_in  = (float*)alloc((size_t)NP * 4);
    float* t2buf    = (float*)alloc((size_t)N * 64 * 4);
    float* t3buf    = (float*)alloc((size_t)N * 32 * 4);
    float* t4buf    = (float*)alloc((size_t)N * 4 * 4);

    hipMemsetAsync(sums, 0, (2048 + 512 + 256 + 256) * 4, stream);

    // ---- slotted atomic-light CSR build (3 kernels) ----
    k_buildbins<<<T, 256, 0, stream>>>(src, dst, E, NBIN, cntD, cntS, bucketD, bucketS);
    k_degout<<<NBIN, 256, 0, stream>>>(bucketS, cntS, N, norm_out);
    k_build<<<NBIN, 256, 0, stream>>>(bucketD, cntD, norm_out, N, rowBE, norm_in, edges);

    int fb = (N + 31) / 32;
    int nb = (N + 255) / 256;
    // L1+L2: t2 = relu(agg(x)*norm@W1+b1)@W2
    k_fused1<<<fb, 512, 0, stream>>>((const float4*)x, edges, rowBE, norm_in,
                                     W1, b1, W2, N, t2buf);
    // L2-agg+L3: t3 = relu(agg(t2)*norm+b2)@W3
    k_fused2<<<fb, 512, 0, stream>>>((const float4*)t2buf, edges, rowBE, norm_in,
                                     b2, W3, N, t3buf);
    // L3-agg+L4-W: t4 = relu(agg(t3)*norm+b3)@W4
    k_aggw4<<<fb, 256, 0, stream>>>((const float4*)t3buf, edges, rowBE,
                                    norm_in, (const float4*)b3, W4, N,
                                    (float4*)t4buf);
    // L4: fused gather(t4)+norm+bias+pool
    k_aggpool<<<nb, 256, 0, stream>>>((const float4*)t4buf, edges, rowBE,
                                      norm_in, b4, gid, N, sums, counts);
    k_div<<<(G * 4 + 255) / 256, 256, 0, stream>>>(sums, counts, G, (float*)d_out);
}

// Round 11
// 178.871 us; speedup vs baseline: 1.1139x; 1.1139x over previous
//
#include <hip/hip_runtime.h>
#include <hip/hip_bf16.h>

// ---------------------------------------------------------------------------
// GCN 4-layer forward on MI355X.
//   - R6: single-pass SLOTTED CSR build (one device atomic per (bin,tile)).
//     Property used by R21/R23: an aligned node block's edges are CONTIGUOUS
//     in the edges[] array (per-bin dst-local scan; 32|512 and 256|512).
//   - R5/R7: float4 gathers, 8-edge unroll.
//   - R10/R11 LDS bank law: AP=33 odd stride -> conflict-free staging.
//   - R12: mega-fusion (agg+GEMM1+GEMM2 in one kernel; h1/agg1/h2 never HBM).
//   - R13 FAILURE: unrolled chunk loops -> compiler pipelined W-loads across
//     barriers -> 256 VGPR + spill. R14 fix: '#pragma unroll 1' chunk loops.
//   - R15 FAILURE: BM 32->64 -> 16 waves/CU -> 98us. Latency-hiding limited.
//   - R18 WIN: 4KB register-dbuf W chunks -> 20.9KB, 28 waves, 76.5us.
//   - R19/R20 FAILURES: forced 8 waves/EU (VGPR 32, MLP collapse); swizzle
//     overhead. R22 FAILURE: W direct-from-global (no prefetch) -> L2 latency
//     in loop-carried dep -> 111us. Prefetch-ahead of W is load-bearing.
//   - R21 WIN: LDS edge staging (fused1/fused2/aggw4). 182us. R23: aggpool
//     staging null (feature-bound).
//   - R24 FAILURE: 512t blocks -> 98us. The 2-pass 256t gather's passes are
//     per-thread INDEPENDENT -> compiler interleaves -> 16 loads in flight;
//     512t halved per-thread MLP. Per-thread MLP is the binding resource.
//   - R25 (this round): R23-exact revert + hoist per-thread rowBE loads
//     above the staging barrier (issue under staging; removes one dependent
//     round from the post-barrier critical path).
//   - pool: wave segmented scan on sorted gid (R1: contended atomics 152us).
// ---------------------------------------------------------------------------

#define TILE 4096   // edges per build tile (256 threads x 16)
#define SLOT 8192   // per-bin slot capacity (bin = 512 nodes, mean ~4080 edges)

// --- build pass 1: tile->LDS, histogram, reserve slot space, scatter -------
__global__ __launch_bounds__(256) void k_buildbins(
        const int* __restrict__ src, const int* __restrict__ dst, int E, int NBIN,
        int* __restrict__ cntD, int* __restrict__ cntS,
        int* __restrict__ bucketD, unsigned short* __restrict__ bucketS) {
    __shared__ int ssrc[TILE];
    __shared__ int sdst[TILE];
    __shared__ int hD[256], hS[256], bD[256], bS[256];
    int t = threadIdx.x;
    hD[t] = 0; hS[t] = 0;
    __syncthreads();
    int base = blockIdx.x * TILE;
    int lim = min(TILE, E - base);
#pragma unroll
    for (int k = 0; k < TILE / 256; k++) {
        int i = k * 256 + t;
        if (i < lim) {
            int d = dst[base + i], sv = src[base + i];
            sdst[i] = d; ssrc[i] = sv;
            atomicAdd(&hD[d >> 9], 1);
            atomicAdd(&hS[sv >> 9], 1);
        }
    }
    __syncthreads();
    if (t < NBIN) {
        bD[t] = (hD[t] > 0) ? atomicAdd(&cntD[t], hD[t]) : 0;
        bS[t] = (hS[t] > 0) ? atomicAdd(&cntS[t], hS[t]) : 0;
        hD[t] = 0; hS[t] = 0;
    }
    __syncthreads();
#pragma unroll
    for (int k = 0; k < TILE / 256; k++) {
        int i = k * 256 + t;
        if (i < lim) {
            int d = sdst[i], sv = ssrc[i];
            int binD = d >> 9, binS = sv >> 9;
            int pD = atomicAdd(&hD[binD], 1) + bD[binD];
            bucketD[binD * SLOT + pD] = (sv << 9) | (d & 511);
            int pS = atomicAdd(&hS[binS], 1) + bS[binS];
            bucketS[binS * SLOT + pS] = (unsigned short)(sv & 511);
        }
    }
}

// --- build pass 2: per-src-bucket LDS count -> norm_out --------------------
__global__ __launch_bounds__(256) void k_degout(const unsigned short* __restrict__ bucketS,
                                                const int* __restrict__ cntS,
                                                int N, float* __restrict__ norm_out) {
    __shared__ int cnt[512];
    int t = threadIdx.x;
    cnt[t] = 0; cnt[t + 256] = 0;
    __syncthreads();
    int bin = blockIdx.x;
    int b0 = bin * SLOT, cn = cntS[bin];
    for (int j = t; j < cn; j += 256) atomicAdd(&cnt[bucketS[b0 + j]], 1);
    __syncthreads();
    int base = bin << 9;
    for (int l = t; l < 512; l += 256) {
        int g = base + l;
        if (g < N) norm_out[g] = rsqrtf(fmaxf((float)cnt[l], 1.0f));
    }
}

// --- build pass 3: per-dst-bucket count+scan -> rowBE/norm_in, place edges -
__global__ __launch_bounds__(256) void k_build(const int* __restrict__ bucketD,
                                               const int* __restrict__ cntDg,
                                               const float* __restrict__ norm_out,
                                               int N, int2* __restrict__ rowBE,
                                               float* __restrict__ norm_in,
                                               int2* __restrict__ edges) {
    __shared__ int cnt[512], sc[512];
    int t = threadIdx.x;
    cnt[t] = 0; cnt[t + 256] = 0;
    __syncthreads();
    int bin = blockIdx.x;
    int b0 = bin * SLOT, cn = cntDg[bin];
    for (int j = t; j < cn; j += 256) atomicAdd(&cnt[bucketD[b0 + j] & 511], 1);
    __syncthreads();
    sc[t] = cnt[t]; sc[t + 256] = cnt[t + 256];
    __syncthreads();
    for (int off = 1; off < 512; off <<= 1) {
        int v0 = (t >= off) ? sc[t - off] : 0;
        int i1 = t + 256;
        int v1 = sc[i1 - off];   // i1 >= 256 >= off always
        __syncthreads();
        sc[t] += v0; sc[i1] += v1;
        __syncthreads();
    }
    int base = bin << 9;
    for (int l = t; l < 512; l += 256) {
        int g = base + l;
        int e = sc[l] - cnt[l];          // exclusive within bucket
        if (g < N) {
            rowBE[g] = make_int2(b0 + e, b0 + sc[l]);
            norm_in[g] = rsqrtf(fmaxf((float)cnt[l], 1.0f));
        }
        cnt[l] = e;                      // becomes placement cursor
    }
    __syncthreads();
    for (int j = t; j < cn; j += 256) {
        int p = bucketD[b0 + j];
        int sv = p >> 9, dl = p & 511;
        int pos = atomicAdd(&cnt[dl], 1);
        edges[b0 + pos] = make_int2(sv, __float_as_int(norm_out[sv]));
    }
}

// shared gather primitive: sum_e w_e * h4[src_e*G + lane], 8-edge unroll.
// 'eb' may point to GLOBAL edges or an LDS-staged copy (forceinline ->
// addrspace inferred at each call site).
template <int G>
__device__ __forceinline__ float4 gather_row(const float4* __restrict__ h4,
                                             const int2* eb,
                                             int j, int end, int lane) {
    float4 acc = make_float4(0.f, 0.f, 0.f, 0.f);
    for (; j + 7 < end; j += 8) {
        int2 e[8];
        float4 v[8];
#pragma unroll
        for (int q = 0; q < 8; q++) e[q] = eb[j + q];
#pragma unroll
        for (int q = 0; q < 8; q++) v[q] = h4[(size_t)e[q].x * G + lane];
#pragma unroll
        for (int q = 0; q < 8; q++) {
            float wq = __int_as_float(e[q].y);
            acc.x += v[q].x * wq; acc.y += v[q].y * wq;
            acc.z += v[q].z * wq; acc.w += v[q].w * wq;
        }
    }
    if (j + 3 < end) {
        int2 e0 = eb[j], e1 = eb[j + 1], e2 = eb[j + 2], e3 = eb[j + 3];
        float4 v0 = h4[(size_t)e0.x * G + lane];
        float4 v1 = h4[(size_t)e1.x * G + lane];
        float4 v2 = h4[(size_t)e2.x * G + lane];
        float4 v3 = h4[(size_t)e3.x * G + lane];
        float w0 = __int_as_float(e0.y), w1 = __int_as_float(e1.y);
        float w2 = __int_as_float(e2.y), w3 = __int_as_float(e3.y);
        acc.x += v0.x * w0 + v1.x * w1 + v2.x * w2 + v3.x * w3;
        acc.y += v0.y * w0 + v1.y * w1 + v2.y * w2 + v3.y * w3;
        acc.z += v0.z * w0 + v1.z * w1 + v2.z * w2 + v3.z * w3;
        acc.w += v0.w * w0 + v1.w * w1 + v2.w * w2 + v3.w * w3;
        j += 4;
    }
    for (; j < end; j++) {
        int2 e = eb[j];
        float4 v = h4[(size_t)e.x * G + lane];
        float w0 = __int_as_float(e.y);
        acc.x += v.x * w0; acc.y += v.y * w0; acc.z += v.z * w0; acc.w += v.w * w0;
    }
    return acc;
}

// --- L1+L2 fused, BM=32 (R18/R21 geometry). GEMM1 32x128 (4x4/thread), GEMM2
// 32x64 (2x4/thread). W streamed in 4KB chunks, REGISTER double-buffered
// ('#pragma unroll 1', R13; prefetch-ahead is load-bearing, R22). R21: block
// edge range staged into Wlds (dead during gather; W chunk 0 in regs).
// R25: per-thread rowBE loads hoisted above the staging barrier.
// LDS = Alds 16.9KB + Wlds 4KB = 20.9KB -> 7 blk/CU = 28 waves.
__global__ __launch_bounds__(256) void k_fused1(const float4* __restrict__ x4,
                        const int2* __restrict__ edges, const int2* __restrict__ rowBE,
                        const float* __restrict__ norm, const float* __restrict__ W1,
                        const float* __restrict__ b1, const float* __restrict__ W2,
                        int N, float* __restrict__ t2) {
    constexpr int AP = 33;                 // float4 slots per k4; AP%8==1 -> free staging
    constexpr int ECAP = 512;              // 4KB of int2 = Wlds footprint
    __shared__ float4 Alds[32 * AP];       // phase1: [k4<16][r<32] ; phase2: [k4<32][r<32]
    __shared__ float  Wlds[1024];          // 4KB W chunk; edge stage during gather
    int2* Elds = (int2*)Wlds;
    int t = threadIdx.x;
    int row0 = blockIdx.x * 32;
    const float4* W1v = (const float4*)W1;
    const float4* W2v = (const float4*)W2;
    float4 wreg = W1v[t];                  // W1 chunk 0 prefetch rides under staging+gather
    // stage this block's contiguous edge range (rows in one bin => ranges
    // are consecutive; 32-aligned blocks never straddle a 512-bin)
    int lastRow = min(row0 + 31, N - 1);
    int eBase = rowBE[row0].x;
    int eLim = min(rowBE[lastRow].y - eBase, ECAP);
    // R25: hoist per-thread row ranges; loads ride under edge staging
    int rr = t >> 4, lane = t & 15;
    int node0 = row0 + rr, node1 = node0 + 16;
    int2 be0 = make_int2(0, 0), be1 = make_int2(0, 0);
    if (node0 < N) be0 = rowBE[node0];
    if (node1 < N) be1 = rowBE[node1];
    float s0 = (node0 < N) ? norm[node0] : 0.f;
    float s1 = (node1 < N) ? norm[node1] : 0.f;
    for (int j = t; j < eLim; j += 256) Elds[j] = edges[eBase + j];
    __syncthreads();
    // gather phase: 2 per-thread-independent rows x 16 float4-lanes
    {
        float4 acc = make_float4(0.f, 0.f, 0.f, 0.f);
        if (node0 < N) {
            if (be0.y - eBase <= eLim)
                acc = gather_row<16>(x4, Elds, be0.x - eBase, be0.y - eBase, lane);
            else
                acc = gather_row<16>(x4, edges, be0.x, be0.y, lane);
            acc.x *= s0; acc.y *= s0; acc.z *= s0; acc.w *= s0;
        }
        Alds[lane * AP + rr] = acc;
        float4 acc2g = make_float4(0.f, 0.f, 0.f, 0.f);
        if (node1 < N) {
            if (be1.y - eBase <= eLim)
                acc2g = gather_row<16>(x4, Elds, be1.x - eBase, be1.y - eBase, lane);
            else
                acc2g = gather_row<16>(x4, edges, be1.x, be1.y, lane);
            acc2g.x *= s1; acc2g.y *= s1; acc2g.z *= s1; acc2g.w *= s1;
        }
        Alds[lane * AP + rr + 16] = acc2g;
    }
    // GEMM1: 32x64 @ 64x128, 4x4/thread (tx<32, ty<8); W1 in 8 chunks of
    // 8 k-rows (4KB), register double-buffered. First barrier also fences
    // Elds reads before Wlds overwrite.
    int tx = t & 31, ty = t >> 5;
    float acc1[4][4] = {};
#pragma unroll 1
    for (int c = 0; c < 8; c++) {
        __syncthreads();                   // prev chunk readers / gather+Elds done
        ((float4*)Wlds)[t] = wreg;
        __syncthreads();
        if (c < 7) wreg = W1v[(c + 1) * 256 + t];   // next chunk under compute
#pragma unroll
        for (int k4l = 0; k4l < 2; k4l++) {
            int k4 = c * 2 + k4l;
            float4 a0 = Alds[k4 * AP + ty * 4 + 0];
            float4 a1 = Alds[k4 * AP + ty * 4 + 1];
            float4 a2 = Alds[k4 * AP + ty * 4 + 2];
            float4 a3 = Alds[k4 * AP + ty * 4 + 3];
            const float* wb = &Wlds[(k4l * 4) * 128 + tx * 4];
            float4 w0 = *(const float4*)(wb);
            float4 w1 = *(const float4*)(wb + 128);
            float4 w2 = *(const float4*)(wb + 256);
            float4 w3 = *(const float4*)(wb + 384);
#define GSTEP(AK, WV) \
            acc1[0][0] += a0.AK * WV.x; acc1[0][1] += a0.AK * WV.y; acc1[0][2] += a0.AK * WV.z; acc1[0][3] += a0.AK * WV.w; \
            acc1[1][0] += a1.AK * WV.x; acc1[1][1] += a1.AK * WV.y; acc1[1][2] += a1.AK * WV.z; acc1[1][3] += a1.AK * WV.w; \
            acc1[2][0] += a2.AK * WV.x; acc1[2][1] += a2.AK * WV.y; acc1[2][2] += a2.AK * WV.z; acc1[2][3] += a2.AK * WV.w; \
            acc1[3][0] += a3.AK * WV.x; acc1[3][1] += a3.AK * WV.y; acc1[3][2] += a3.AK * WV.z; acc1[3][3] += a3.AK * WV.w;
            GSTEP(x, w0) GSTEP(y, w1) GSTEP(z, w2) GSTEP(w, w3)
        }
    }
    __syncthreads();                       // last GEMM1 A/W reads done
    float4 bb = *(const float4*)(b1 + tx * 4);
    wreg = W2v[t];                         // W2 chunk 0 prefetch rides under H1 store
    float4 h[4];
#pragma unroll
    for (int i = 0; i < 4; i++) {
        h[i].x = fmaxf(acc1[i][0] + bb.x, 0.f);
        h[i].y = fmaxf(acc1[i][1] + bb.y, 0.f);
        h[i].z = fmaxf(acc1[i][2] + bb.z, 0.f);
        h[i].w = fmaxf(acc1[i][3] + bb.w, 0.f);
    }
#pragma unroll
    for (int i = 0; i < 4; i++) Alds[tx * AP + ty * 4 + i] = h[i];   // H1: [k4=tx][r]
    // GEMM2: 32x128 @ 128x64, 2x4/thread (tx2<16, ty2<16); W2 in 8 chunks of
    // 16 k-rows (4KB), register double-buffered
    int tx2 = t & 15, ty2 = t >> 4;
    float acc2[2][4] = {};
#pragma unroll 1
    for (int c = 0; c < 8; c++) {
        __syncthreads();                   // publishes H1 (c==0) / prev readers done
        ((float4*)Wlds)[t] = wreg;
        __syncthreads();
        if (c < 7) wreg = W2v[(c + 1) * 256 + t];
#pragma unroll
        for (int k4l = 0; k4l < 4; k4l++) {
            int k4 = c * 4 + k4l;
            float4 a0 = Alds[k4 * AP + ty2 * 2 + 0];
            float4 a1 = Alds[k4 * AP + ty2 * 2 + 1];
            const float* wb = &Wlds[(k4l * 4) * 64 + tx2 * 4];
            float4 w0 = *(const float4*)(wb);
            float4 w1 = *(const float4*)(wb + 64);
            float4 w2 = *(const float4*)(wb + 128);
            float4 w3 = *(const float4*)(wb + 192);
#define GSTEP2(AK, WV) \
            acc2[0][0] += a0.AK * WV.x; acc2[0][1] += a0.AK * WV.y; acc2[0][2] += a0.AK * WV.z; acc2[0][3] += a0.AK * WV.w; \
            acc2[1][0] += a1.AK * WV.x; acc2[1][1] += a1.AK * WV.y; acc2[1][2] += a1.AK * WV.z; acc2[1][3] += a1.AK * WV.w;
            GSTEP2(x, w0) GSTEP2(y, w1) GSTEP2(z, w2) GSTEP2(w, w3)
#undef GSTEP2
        }
    }
#pragma unroll
    for (int i = 0; i < 2; i++) {
        int grow = row0 + ty2 * 2 + i;
        if (grow < N) {
            float4 o = make_float4(acc2[i][0], acc2[i][1], acc2[i][2], acc2[i][3]);
            *(float4*)(t2 + (size_t)grow * 64 + tx2 * 4) = o;
        }
    }
#undef GSTEP
}

// --- L2-agg + L3 fused, BM=32: per 32-row block:
//   H2 = relu(agg(t2)*norm + b2)  (gather -> LDS, edges staged in Wlds)
//   t3 = H2@W3                    (-> global)
// W3 (8KB) prefetched into 2 regs during staging+gather. R25: rowBE hoisted.
__global__ __launch_bounds__(256) void k_fused2(const float4* __restrict__ t2_4,
                        const int2* __restrict__ edges, const int2* __restrict__ rowBE,
                        const float* __restrict__ norm, const float* __restrict__ b2,
                        const float* __restrict__ W3, int N, float* __restrict__ t3) {
    constexpr int AP = 33;
    constexpr int ECAP = 1024;             // 8KB of int2 = Wlds footprint
    __shared__ float4 Alds[16 * AP];       // [k4<16][r<32]
    __shared__ float  Wlds[64 * 32];       // W3; edge stage during gather
    int2* Elds = (int2*)Wlds;
    int t = threadIdx.x;
    int row0 = blockIdx.x * 32;
    float4 wr0 = ((const float4*)W3)[t];       // W3 prefetch rides under staging+gather
    float4 wr1 = ((const float4*)W3)[t + 256];
    int lastRow = min(row0 + 31, N - 1);
    int eBase = rowBE[row0].x;
    int eLim = min(rowBE[lastRow].y - eBase, ECAP);
    // R25: hoist per-thread row ranges
    int rr = t >> 4, lane = t & 15;
    int node0 = row0 + rr, node1 = node0 + 16;
    int2 be0 = make_int2(0, 0), be1 = make_int2(0, 0);
    if (node0 < N) be0 = rowBE[node0];
    if (node1 < N) be1 = rowBE[node1];
    float s0 = (node0 < N) ? norm[node0] : 0.f;
    float s1 = (node1 < N) ? norm[node1] : 0.f;
    for (int j = t; j < eLim; j += 256) Elds[j] = edges[eBase + j];
    __syncthreads();
    {
        float4 b = ((const float4*)b2)[lane];
        float4 acc = make_float4(0.f, 0.f, 0.f, 0.f);
        if (node0 < N) {
            if (be0.y - eBase <= eLim)
                acc = gather_row<16>(t2_4, Elds, be0.x - eBase, be0.y - eBase, lane);
            else
                acc = gather_row<16>(t2_4, edges, be0.x, be0.y, lane);
            acc.x = fmaxf(acc.x * s0 + b.x, 0.f);
            acc.y = fmaxf(acc.y * s0 + b.y, 0.f);
            acc.z = fmaxf(acc.z * s0 + b.z, 0.f);
            acc.w = fmaxf(acc.w * s0 + b.w, 0.f);
        }
        Alds[lane * AP + rr] = acc;
        float4 accB = make_float4(0.f, 0.f, 0.f, 0.f);
        if (node1 < N) {
            if (be1.y - eBase <= eLim)
                accB = gather_row<16>(t2_4, Elds, be1.x - eBase, be1.y - eBase, lane);
            else
                accB = gather_row<16>(t2_4, edges, be1.x, be1.y, lane);
            accB.x = fmaxf(accB.x * s1 + b.x, 0.f);
            accB.y = fmaxf(accB.y * s1 + b.y, 0.f);
            accB.z = fmaxf(accB.z * s1 + b.z, 0.f);
            accB.w = fmaxf(accB.w * s1 + b.w, 0.f);
        }
        Alds[lane * AP + rr + 16] = accB;
    }
    __syncthreads();                       // all Elds reads done before W3 overwrite
    ((float4*)Wlds)[t] = wr0;
    ((float4*)Wlds)[t + 256] = wr1;
    __syncthreads();
    // GEMM3: 32x64 @ 64x32, 1 row x 4 cols/thread (tx<8, ty<32)
    int tx = t & 7, ty = t >> 3;
    float acc3[4] = {};
#pragma unroll 2
    for (int k4 = 0; k4 < 16; k4++) {
        float4 a = Alds[k4 * AP + ty];
        const float* wb = &Wlds[(k4 * 4) * 32 + tx * 4];
        float4 w0 = *(const float4*)(wb);
        float4 w1 = *(const float4*)(wb + 32);
        float4 w2 = *(const float4*)(wb + 64);
        float4 w3 = *(const float4*)(wb + 96);
        acc3[0] += a.x * w0.x + a.y * w1.x + a.z * w2.x + a.w * w3.x;
        acc3[1] += a.x * w0.y + a.y * w1.y + a.z * w2.y + a.w * w3.y;
        acc3[2] += a.x * w0.z + a.y * w1.z + a.z * w2.z + a.w * w3.z;
        acc3[3] += a.x * w0.w + a.y * w1.w + a.z * w2.w + a.w * w3.w;
    }
    int grow = row0 + ty;
    if (grow < N) {
        float4 o = make_float4(acc3[0], acc3[1], acc3[2], acc3[3]);
        *(float4*)(t3 + (size_t)grow * 32 + tx * 4) = o;
    }
}

// agg3 + W4 fused (D=32): h3 = relu(agg(t3)*norm+b3) in regs (never stored),
// t4[node] = h3 @ W4 via per-lane partials + 8-lane __shfl_xor reduce.
// R21: edges staged into dedicated 4KB LDS (kernel is far below LDS cap).
__global__ __launch_bounds__(256) void k_aggw4(const float4* __restrict__ h4,
                        const int2* __restrict__ edges, const int2* __restrict__ rowBE,
                        const float* __restrict__ norm, const float4* __restrict__ b3_4,
                        const float* __restrict__ W4, int n, float4* __restrict__ t4) {
    __shared__ float w[128];
    __shared__ int2 Elds[512];
    int t = threadIdx.x;
    if (t < 128) w[t] = W4[t];
    int row0 = blockIdx.x * 32;
    int lastRow = min(row0 + 31, n - 1);
    int eBase = rowBE[row0].x;
    int eLim = min(rowBE[lastRow].y - eBase, 512);
    for (int j = t; j < eLim; j += 256) Elds[j] = edges[eBase + j];
    __syncthreads();
    int node = row0 + t / 8;
    int lane = t % 8;
    if (node >= n) return;
    float4 wr0 = ((const float4*)w)[4 * lane + 0];
    float4 wr1 = ((const float4*)w)[4 * lane + 1];
    float4 wr2 = ((const float4*)w)[4 * lane + 2];
    float4 wr3 = ((const float4*)w)[4 * lane + 3];
    int2 be = rowBE[node];
    float4 acc;
    if (be.y - eBase <= eLim)
        acc = gather_row<8>(h4, Elds, be.x - eBase, be.y - eBase, lane);
    else
        acc = gather_row<8>(h4, edges, be.x, be.y, lane);
    float s = norm[node];
    float4 b = b3_4[lane];
    float hx = fmaxf(acc.x * s + b.x, 0.f);
    float hy = fmaxf(acc.y * s + b.y, 0.f);
    float hz = fmaxf(acc.z * s + b.z, 0.f);
    float hw = fmaxf(acc.w * s + b.w, 0.f);
    float4 p;
    p.x = hx * wr0.x + hy * wr1.x + hz * wr2.x + hw * wr3.x;
    p.y = hx * wr0.y + hy * wr1.y + hz * wr2.y + hw * wr3.y;
    p.z = hx * wr0.z + hy * wr1.z + hz * wr2.z + hw * wr3.z;
    p.w = hx * wr0.w + hy * wr1.w + hz * wr2.w + hw * wr3.w;
#pragma unroll
    for (int m = 1; m < 8; m <<= 1) {
        p.x += __shfl_xor(p.x, m);
        p.y += __shfl_xor(p.y, m);
        p.z += __shfl_xor(p.z, m);
        p.w += __shfl_xor(p.w, m);
    }
    if (lane == 0) t4[node] = p;
}

// L4 fused: per node (1 thread): acc = sum_e t4[src_e]*w_e ; v = acc*norm+b4 ;
// wave segmented-scan pool on sorted gid -> atomics.
// R23: block covers 256 nodes = half a 512-bin -> contiguous edge range;
// stage into 24KB LDS (grid ~1.5 blocks/CU, LDS is free capacity here).
__global__ __launch_bounds__(256) void k_aggpool(const float4* __restrict__ t4,
                        const int2* __restrict__ edges, const int2* __restrict__ rowBE,
                        const float* __restrict__ norm, const float* __restrict__ b4,
                        const int* __restrict__ gid, int N,
                        float* __restrict__ sums, float* __restrict__ counts) {
    constexpr int ECAP = 3072;             // 24KB; mean 2048 edges/block, >>6 sigma
    __shared__ int2 Elds[ECAP];
    int t = threadIdx.x;
    int row0 = blockIdx.x * blockDim.x;    // row0 < N guaranteed by grid
    int lastRow = min(row0 + 255, N - 1);
    int eBase = rowBE[row0].x;
    int eLim = min(rowBE[lastRow].y - eBase, ECAP);
    for (int j = t; j < eLim; j += 256) Elds[j] = edges[eBase + j];
    __syncthreads();
    int n = row0 + t;
    int lane = t & 63;
    bool valid = (n < N);
    float v0 = 0.f, v1 = 0.f, v2 = 0.f, v3 = 0.f, cnt = 0.f;
    int g = -1;
    if (valid) {
        g = gid[n];
        int2 be = rowBE[n];
        float4 acc;
        if (be.y - eBase <= eLim)
            acc = gather_row<1>(t4, Elds, be.x - eBase, be.y - eBase, 0);
        else
            acc = gather_row<1>(t4, edges, be.x, be.y, 0);
        float s = norm[n];
        v0 = acc.x * s + b4[0];
        v1 = acc.y * s + b4[1];
        v2 = acc.z * s + b4[2];
        v3 = acc.w * s + b4[3];
        cnt = 1.f;
    }
#pragma unroll
    for (int off = 1; off < 64; off <<= 1) {
        float u0 = __shfl_up(v0, off);
        float u1 = __shfl_up(v1, off);
        float u2 = __shfl_up(v2, off);
        float u3 = __shfl_up(v3, off);
        float uc = __shfl_up(cnt, off);
        int   ug = __shfl_up(g, off);
        if (lane >= off && ug == g) { v0 += u0; v1 += u1; v2 += u2; v3 += u3; cnt += uc; }
    }
    int gnext = __shfl_down(g, 1);
    bool boundary = (lane == 63) || (gnext != g);
    if (boundary && valid) {
        atomicAdd(&sums[g * 4 + 0], v0);
        atomicAdd(&sums[g * 4 + 1], v1);
        atomicAdd(&sums[g * 4 + 2], v2);
        atomicAdd(&sums[g * 4 + 3], v3);
        atomicAdd(&counts[g], cnt);
    }
}

__global__ void k_div(const float* __restrict__ sums, const float* __restrict__ counts,
                      int G, float* __restrict__ out) {
    int idx = blockIdx.x * blockDim.x + threadIdx.x;
    if (idx >= G * 4) return;
    out[idx] = sums[idx] / fmaxf(counts[idx >> 2], 1.0f);
}

extern "C" void kernel_launch(void* const* d_in, const int* in_sizes, int n_in,
                              void* d_out, int out_size, void* d_ws, size_t ws_size,
                              hipStream_t stream) {
    const float* x  = (const float*)d_in[0];
    const float* W1 = (const float*)d_in[1];
    const float* b1 = (const float*)d_in[2];
    const float* W2 = (const float*)d_in[3];
    const float* b2 = (const float*)d_in[4];
    const float* W3 = (const float*)d_in[5];
    const float* b3 = (const float*)d_in[6];
    const float* W4 = (const float*)d_in[7];
    const float* b4 = (const float*)d_in[8];
    const int* src = (const int*)d_in[9];
    const int* dst = (const int*)d_in[10];
    const int* gid = (const int*)d_in[11];

    const int N = in_sizes[0] / 64;
    const int E = in_sizes[9];
    const int G = out_size / 4;
    const int NP = ((N + 63) / 64) * 64;
    const int NBIN = (N + 511) >> 9;          // coarse bins (<=256 for N<=131072)
    const int T = (E + TILE - 1) / TILE;      // build tiles

    char* ws = (char*)d_ws;
    size_t off = 0;
    auto alloc = [&](size_t bytes) -> void* {
        void* p = (void*)(ws + off);
        off += (bytes + 255) & ~(size_t)255;
        return p;
    };
    float* sums     = (float*)alloc(2048 * 4);   // 500*4 used
    float* counts   = (float*)alloc(512 * 4);
    int*   cntD     = (int*)alloc(256 * 4);
    int*   cntS     = (int*)alloc(256 * 4);
    int*   bucketD  = (int*)alloc((size_t)NBIN * SLOT * 4);
    unsigned short* bucketS = (unsigned short*)alloc((size_t)NBIN * SLOT * 2);
    int2*  edges    = (int2*)alloc((size_t)NBIN * SLOT * 8);
    int2*  rowBE    = (int2*)alloc((size_t)NP * 8);
    float* norm_out = (float*)alloc((size_t)NP * 4);
    float* norm_in  = (float*)alloc((size_t)NP * 4);
    float* t2buf    = (float*)alloc((size_t)N * 64 * 4);
    float* t3buf    = (float*)alloc((size_t)N * 32 * 4);
    float* t4buf    = (float*)alloc((size_t)N * 4 * 4);

    hipMemsetAsync(sums, 0, (2048 + 512 + 256 + 256) * 4, stream);

    // ---- slotted atomic-light CSR build (3 kernels) ----
    k_buildbins<<<T, 256, 0, stream>>>(src, dst, E, NBIN, cntD, cntS, bucketD, bucketS);
    k_degout<<<NBIN, 256, 0, stream>>>(bucketS, cntS, N, norm_out);
    k_build<<<NBIN, 256, 0, stream>>>(bucketD, cntD, norm_out, N, rowBE, norm_in, edges);

    int fb = (N + 31) / 32;
    int nb = (N + 255) / 256;
    // L1+L2: t2 = relu(agg(x)*norm@W1+b1)@W2
    k_fused1<<<fb, 256, 0, stream>>>((const float4*)x, edges, rowBE, norm_in,
                                     W1, b1, W2, N, t2buf);
    // L2-agg+L3: t3 = relu(agg(t2)*norm+b2)@W3
    k_fused2<<<fb, 256, 0, stream>>>((const float4*)t2buf, edges, rowBE, norm_in,
                                     b2, W3, N, t3buf);
    // L3-agg+L4-W: t4 = relu(agg(t3)*norm+b3)@W4
    k_aggw4<<<fb, 256, 0, stream>>>((const float4*)t3buf, edges, rowBE,
                                    norm_in, (const float4*)b3, W4, N,
                                    (float4*)t4buf);
    // L4: fused gather(t4)+norm+bias+pool
    k_aggpool<<<nb, 256, 0, stream>>>((const float4*)t4buf, edges, rowBE,
                                      norm_in, b4, gid, N, sums, counts);
    k_div<<<(G * 4 + 255) / 256, 256, 0, stream>>>(sums, counts, G, (float*)d_out);
}